// Round 1
// baseline (2376.611 us; speedup 1.0000x reference)
//
#include <hip/hip_runtime.h>

#define B_ 128
#define T_ 512
#define I_ 64
#define R_ 512
#define O_ 64
#define NG 8          // batch groups (16 batches each)
#define GB 16

typedef _Float16 f16;
typedef __attribute__((ext_vector_type(8))) _Float16 half8;
typedef __attribute__((ext_vector_type(4))) _Float16 half4;
typedef __attribute__((ext_vector_type(4))) float f32x4;

#define MFMA16 __builtin_amdgcn_mfma_f32_16x16x32_f16

__device__ __forceinline__ float tanh_fast(float x) {
    // 1 - 2/(e^{2x}+1), reciprocal via v_rcp_f32 (approx, ~1 ulp) instead of the
    // precise-div sequence (~8 VALU ops/elem saved; error invisible under f16).
    float e = __expf(2.0f * x);
    return 1.0f - 2.0f * __builtin_amdgcn_rcpf(e + 1.0f);
}

__device__ __forceinline__ half8 cvt_h8(const float4 a, const float4 b) {
    half8 r;
    r[0] = (f16)a.x; r[1] = (f16)a.y; r[2] = (f16)a.z; r[3] = (f16)a.w;
    r[4] = (f16)b.x; r[5] = (f16)b.y; r[6] = (f16)b.z; r[7] = (f16)b.w;
    return r;
}

__device__ __forceinline__ unsigned pack2(float a, float b) {
    union { f16 h[2]; unsigned u; } r;
    r.h[0] = (f16)a; r.h[1] = (f16)b; return r.u;
}

// ---------------- pre-kernel: u[t][g][r][b] (f16) = U_h . x + b_h ----------------
// (unchanged math/layout; additionally zeroes the cross-block flags in `out`)
__global__ void __launch_bounds__(256) pre_kernel(
    const float* __restrict__ x_pred, const float* __restrict__ b_h,
    const float* __restrict__ U_h, f16* __restrict__ ubuf, int* __restrict__ flags)
{
    const int tid = threadIdx.x;
    if (blockIdx.x == 0) { flags[tid] = 0; flags[tid + 256] = 0; }

    const int w = tid >> 6, l = tid & 63, lg = l >> 4, ln = l & 15;
    const int g = blockIdx.x & 7, tc = blockIdx.x >> 3;   // 4 timesteps per block
    const int b0 = g * GB;

    half8 uf[8][2];
    float bh[8];
    #pragma unroll
    for (int j = 0; j < 8; ++j) {
        const int rt = 128 * w + 16 * j;
        bh[j] = b_h[rt + ln];
        #pragma unroll
        for (int ks = 0; ks < 2; ++ks) {
            const float* p = U_h + (size_t)(rt + ln) * I_ + 32 * ks + 8 * lg;
            uf[j][ks] = cvt_h8(*(const float4*)p, *(const float4*)(p + 4));
        }
    }
    for (int tt = 0; tt < 4; ++tt) {
        const int t = tc * 4 + tt;
        half8 xf[2];
        #pragma unroll
        for (int ks = 0; ks < 2; ++ks) {
            const float* p = x_pred + ((size_t)(b0 + ln) * T_ + t) * I_ + 32 * ks + 8 * lg;
            xf[ks] = cvt_h8(*(const float4*)p, *(const float4*)(p + 4));
        }
        f16* ut = ubuf + (size_t)(t * NG + g) * 8192;
        #pragma unroll
        for (int j = 0; j < 8; ++j) {
            f32x4 acc = {0.f, 0.f, 0.f, 0.f};
            acc = MFMA16(xf[0], uf[j][0], acc, 0, 0, 0);
            acc = MFMA16(xf[1], uf[j][1], acc, 0, 0, 0);
            const int rt = 128 * w + 16 * j;
            half4 hv;
            #pragma unroll
            for (int q = 0; q < 4; ++q) hv[q] = (f16)(acc[q] + bh[j]);
            *(half4*)((char*)ut + (size_t)(rt + ln) * 32 + 8 * lg) = hv;
        }
    }
}

// ---- RNN kernel: 16 blocks = 8 groups x 2 row-halves. Each block owns 256 rows
// of its group; W fully register-resident (32 frags/wave = 128 VGPR). Partner's
// h-half is exchanged through the global h-history slot with a per-step
// release/acquire flag (agent scope). Operands swapped: mfma(W, h) puts 4
// CONSECUTIVE rows per lane -> vectorized b64 publish, float4 x_last.
__global__ void __launch_bounds__(512, 2) rnn_kernel(
    const float* __restrict__ h0, const float* __restrict__ W_h,
    f16* __restrict__ uh, float* __restrict__ out)
{
    __shared__ __align__(16) char smem[2][16384];   // double-buffered h, [b][r] f16, XOR-swizzled
    const int tid = threadIdx.x;
    const int w = tid >> 6, l = tid & 63, lg = l >> 4, ln = l & 15;
    const int gid = blockIdx.x;
    const int g = gid & 7, hf = gid >> 3;           // group, row-half
    const int pgid = gid ^ 8;                       // partner block (other half, same group)
    const int b0 = g * GB;
    const int rw = hf * 256 + w * 32;               // wave's first output row
    int* flags = (int*)out;                         // lives in y-region (dead until y_kernel); 128B strided

    // ---- stage W rows [rw, rw+32): wfr[j][k]: k<8 = own-half ks, k>=8 = partner-half ks.
    half8 wfr[2][16];
    #pragma unroll
    for (int j = 0; j < 2; ++j) {
        const float* wr = W_h + (size_t)(rw + 16 * j + ln) * R_;
        #pragma unroll
        for (int k = 0; k < 16; ++k) {
            const int ks = (k < 8) ? (8 * hf + k) : (8 * (1 - hf) + (k - 8));
            const float* p = wr + 32 * ks + 8 * lg;
            wfr[j][k] = cvt_h8(*(const float4*)p, *(const float4*)(p + 4));
        }
    }
    // ---- stage FULL h0 into buffer 0 (both halves; only step 0 needs partner rows) ----
    {
        const int b = tid >> 5, r0 = (tid & 31) * 16;
        const int sb = (b & 7) << 4;
        const float* hp = h0 + (size_t)(b0 + b) * R_ + r0;
        #pragma unroll
        for (int q = 0; q < 4; ++q) {
            float4 v = *(const float4*)(hp + 4 * q);
            uint2 pk;
            pk.x = pack2(v.x, v.y); pk.y = pack2(v.z, v.w);
            *(uint2*)(&smem[0][b * 1024 + ((2 * (r0 + 4 * q)) ^ sb)]) = pk;
        }
    }
    // ---- prefetch u[0] (scalar f16 from pre's [r][b] layout) ----
    f16 uu[8];
    {
        const f16* up = uh + (size_t)g * 8192;
        #pragma unroll
        for (int j = 0; j < 2; ++j)
            #pragma unroll
            for (int q = 0; q < 4; ++q)
                uu[4 * j + q] = up[(rw + 16 * j + 4 * lg + q) * 16 + ln];
    }
    __syncthreads();   // drains vmcnt (u[0] in regs) + lgkm (h0 staged)
    if (tid == 0) __hip_atomic_store(flags + gid * 32, 1, __ATOMIC_RELEASE, __HIP_MEMORY_SCOPE_AGENT);

    const int asb = (ln & 7) << 4;                   // LDS swizzle (b = ln)
    const int hbase = ln * 1024 + 512 * hf;          // own-half byte base in [b][r]
    const int pbase = ln * 1024 + 512 * (1 - hf);    // partner-half byte base

    #pragma unroll 1
    for (int t = 0; t < T_; ++t) {
        char* hc = smem[t & 1];
        char* hn = smem[(t & 1) ^ 1];
        f16* slot = uh + (size_t)(t * NG + g) * 8192;   // u[t] in, h[t+1] out ([b][r])
        const bool lastt = (t == T_ - 1);

        // acc <- u[t] (prefetched last step; completion ordered before our flag t+1,
        // which gates the partner's overwrite of slot t)
        f32x4 acc[2];
        #pragma unroll
        for (int j = 0; j < 2; ++j)
            acc[j] = (f32x4){(float)uu[4*j+0], (float)uu[4*j+1], (float)uu[4*j+2], (float)uu[4*j+3]};

        // wait for partner h[t] (t>=1) / partner-init (t==0: guards our slot-0 stores).
        // In lockstep the flag is a full step old -> poll passes on first read.
        if (l == 0) {
            while (__hip_atomic_load(flags + pgid * 32, __ATOMIC_ACQUIRE, __HIP_MEMORY_SCOPE_AGENT) < t + 1)
                __builtin_amdgcn_s_sleep(1);
        }
        // partner-half B-frags from global slot t-1 (L2/L3); latency hides under own-half MFMAs
        half8 pf[8];
        if (t > 0) {
            const char* ps = (const char*)(slot - NG * 8192) + pbase;
            #pragma unroll
            for (int k = 0; k < 8; ++k)
                pf[k] = *(const half8*)(ps + 64 * k + 16 * lg);
        }
        // prefetch u[t+1] (own rows only; race-free: partner writes slot t+1 only after our flag t+2)
        if (!lastt) {
            const f16* un = uh + (size_t)((t + 1) * NG + g) * 8192;
            #pragma unroll
            for (int j = 0; j < 2; ++j)
                #pragma unroll
                for (int q = 0; q < 4; ++q)
                    uu[4 * j + q] = un[(rw + 16 * j + 4 * lg + q) * 16 + ln];
        }
        // ---- own-half: 8 ks from LDS ----
        #pragma unroll
        for (int k = 0; k < 8; ++k) {
            half8 ah = *(const half8*)(hc + hbase + ((64 * k + 16 * lg) ^ asb));
            acc[0] = MFMA16(wfr[0][k], ah, acc[0], 0, 0, 0);
            acc[1] = MFMA16(wfr[1][k], ah, acc[1], 0, 0, 0);
        }
        // ---- partner-half: 8 ks from regs (t>0) or LDS h0 (t==0) ----
        if (t > 0) {
            #pragma unroll
            for (int k = 0; k < 8; ++k) {
                acc[0] = MFMA16(wfr[0][8 + k], pf[k], acc[0], 0, 0, 0);
                acc[1] = MFMA16(wfr[1][8 + k], pf[k], acc[1], 0, 0, 0);
            }
        } else {
            #pragma unroll
            for (int k = 0; k < 8; ++k) {
                half8 ah = *(const half8*)(hc + pbase + ((64 * k + 16 * lg) ^ asb));
                acc[0] = MFMA16(wfr[0][8 + k], ah, acc[0], 0, 0, 0);
                acc[1] = MFMA16(wfr[1][8 + k], ah, acc[1], 0, 0, 0);
            }
        }
        // ---- finalize: lane holds 4 CONSECUTIVE rows (batch=ln) -> b64 publishes ----
        #pragma unroll
        for (int j = 0; j < 2; ++j) {
            const int rb = 2 * (rw + 16 * j + 4 * lg);   // byte offset of 4-row group
            float hv0 = tanh_fast(acc[j][0]), hv1 = tanh_fast(acc[j][1]);
            float hv2 = tanh_fast(acc[j][2]), hv3 = tanh_fast(acc[j][3]);
            uint2 pk;
            pk.x = pack2(hv0, hv1); pk.y = pack2(hv2, hv3);
            *(uint2*)((char*)slot + ln * 1024 + rb) = pk;        // h history, plain [b][r]
            if (!lastt) {
                *(uint2*)(hn + ln * 1024 + (rb ^ asb)) = pk;     // LDS next buffer (swizzled)
            } else {
                float* xb = out + (size_t)B_ * T_ * O_ + (size_t)(b0 + ln) * R_ + (rw + 16 * j + 4 * lg);
                float4 xv = make_float4(hv0, hv1, hv2, hv3);
                *(float4*)xb = xv;
                *(float4*)(xb + (size_t)B_ * R_) = xv;
            }
        }
        // vmcnt(0)+lgkmcnt(0)+barrier: slot stores acked to L2 and LDS published
        // before the release flag (whose wbl2 flushes all waves' lines).
        __syncthreads();
        if (tid == 0) __hip_atomic_store(flags + gid * 32, t + 2, __ATOMIC_RELEASE, __HIP_MEMORY_SCOPE_AGENT);
    }
}

// ---------------- post-kernel: y[b][t][o] = W_out . h + b_out ----------------
// h history is now [b][r] -> vectorized b128 loads instead of scalar gathers.
__global__ void __launch_bounds__(256) y_kernel(
    const f16* __restrict__ hbuf, const float* __restrict__ W_out,
    const float* __restrict__ b_out, float* __restrict__ out)
{
    const int tid = threadIdx.x;
    const int w = tid >> 6, l = tid & 63, lg = l >> 4, ln = l & 15;
    const int g = blockIdx.x & 7, tc = blockIdx.x >> 3;
    const int b0 = g * GB;

    half8 wf[16];
    #pragma unroll
    for (int ks = 0; ks < 16; ++ks) {
        const float* p = W_out + (size_t)(16 * w + ln) * R_ + 32 * ks + 8 * lg;
        wf[ks] = cvt_h8(*(const float4*)p, *(const float4*)(p + 4));
    }
    const float bo = b_out[16 * w + ln];

    for (int tt = 0; tt < 4; ++tt) {
        const int t = tc * 4 + tt;
        const char* hb = (const char*)(hbuf + (size_t)(t * NG + g) * 8192);   // [b][r]
        f32x4 acc = {0.f, 0.f, 0.f, 0.f};
        #pragma unroll
        for (int ks = 0; ks < 16; ++ks) {
            half8 a = *(const half8*)(hb + ln * 1024 + 64 * ks + 16 * lg);
            acc = MFMA16(a, wf[ks], acc, 0, 0, 0);
        }
        #pragma unroll
        for (int q = 0; q < 4; ++q) {
            const int b = 4 * lg + q;
            out[((size_t)(b0 + b) * T_ + t) * O_ + 16 * w + ln] = acc[q] + bo;
        }
    }
}

extern "C" void kernel_launch(void* const* d_in, const int* in_sizes, int n_in,
                              void* d_out, int out_size, void* d_ws, size_t ws_size,
                              hipStream_t stream) {
    const float* x_pred = (const float*)d_in[0];
    const float* h0     = (const float*)d_in[1];
    const float* W_h    = (const float*)d_in[2];
    const float* b_h    = (const float*)d_in[3];
    const float* U_h    = (const float*)d_in[4];
    const float* W_out  = (const float*)d_in[5];
    const float* b_out  = (const float*)d_in[6];
    float* out = (float*)d_out;

    // workspace: u[t][g] slabs (f16, 64 MiB), overwritten in-place by h[t+1] ([b][r]).
    f16* ubuf = (f16*)d_ws;
    int* flags = (int*)out;   // y-region scratch, overwritten by y_kernel

    pre_kernel<<<dim3(NG * 128), dim3(256), 0, stream>>>(x_pred, b_h, U_h, ubuf, flags);
    rnn_kernel<<<dim3(16), dim3(512), 0, stream>>>(h0, W_h, ubuf, out);
    y_kernel<<<dim3(NG * 128), dim3(256), 0, stream>>>(ubuf, W_out, b_out, out);
}

// Round 2
// 1913.602 us; speedup vs baseline: 1.2420x; 1.2420x over previous
//
#include <hip/hip_runtime.h>

#define B_ 128
#define T_ 512
#define I_ 64
#define R_ 512
#define O_ 64
#define NG 8          // batch groups (16 batches each); 1 block per group
#define GB 16

typedef _Float16 f16;
typedef __attribute__((ext_vector_type(8))) _Float16 half8;
typedef __attribute__((ext_vector_type(4))) float f32x4;

#define MFMA16 __builtin_amdgcn_mfma_f32_16x16x32_f16

// RNN block: 512 threads = 8 waves, wave w owns rows [64w, 64w+64) = 4 m-tiles.
// W_h A-frags per wave: 64 (fi = ks*4 + j):
//   fi < 15  -> LDS   (reads overlap the h B-frag read ramp at phase start)
//   fi >= 15 -> VGPR/AGPR (49 frags)
#define NLW 15
#define NRW 49
#define WLDS_BYTES (8 * NLW * 1024)            // 122880
#define HOFF WLDS_BYTES
#define HBYTES 16384
#define SMEM_TOTAL (WLDS_BYTES + 2 * HBYTES)   // 155648 <= 163840

__device__ __forceinline__ float tanh_fast(float x) {
    // 1 - 2/(e^{2x}+1); reciprocal via v_rcp_f32 (~1 ulp, invisible under f16).
    float e = __expf(2.0f * x);
    return 1.0f - 2.0f * __builtin_amdgcn_rcpf(e + 1.0f);
}

__device__ __forceinline__ half8 cvt_h8(const float4 a, const float4 b) {
    half8 r;
    r[0] = (f16)a.x; r[1] = (f16)a.y; r[2] = (f16)a.z; r[3] = (f16)a.w;
    r[4] = (f16)b.x; r[5] = (f16)b.y; r[6] = (f16)b.z; r[7] = (f16)b.w;
    return r;
}

__device__ __forceinline__ unsigned pack2(float a, float b) {
    union { f16 h[2]; unsigned u; } r;
    r.h[0] = (f16)a; r.h[1] = (f16)b; return r.u;
}

// ------------- pre-kernel: u[t][g][b][r] (f16) = U_h . x + b_h  ([b][r]!) -------------
// Operand-swapped (mfma(U, x)): D rows = U rows (4 consecutive per lane), cols = batch.
__global__ void __launch_bounds__(256) pre_kernel(
    const float* __restrict__ x_pred, const float* __restrict__ b_h,
    const float* __restrict__ U_h, f16* __restrict__ ubuf)
{
    const int tid = threadIdx.x;
    const int w = tid >> 6, l = tid & 63, lg = l >> 4, ln = l & 15;
    const int g = blockIdx.x & 7, tc = blockIdx.x >> 3;   // 4 timesteps per block
    const int b0 = g * GB;

    half8 uf[8][2];
    float4 bh4[8];
    #pragma unroll
    for (int j = 0; j < 8; ++j) {
        const int rt = 128 * w + 16 * j;
        bh4[j] = *(const float4*)(b_h + rt + 4 * lg);   // bias for rows rt+4lg..+3
        #pragma unroll
        for (int ks = 0; ks < 2; ++ks) {
            const float* p = U_h + (size_t)(rt + ln) * I_ + 32 * ks + 8 * lg;
            uf[j][ks] = cvt_h8(*(const float4*)p, *(const float4*)(p + 4));
        }
    }
    for (int tt = 0; tt < 4; ++tt) {
        const int t = tc * 4 + tt;
        half8 xf[2];
        #pragma unroll
        for (int ks = 0; ks < 2; ++ks) {
            const float* p = x_pred + ((size_t)(b0 + ln) * T_ + t) * I_ + 32 * ks + 8 * lg;
            xf[ks] = cvt_h8(*(const float4*)p, *(const float4*)(p + 4));
        }
        char* ut = (char*)ubuf + (size_t)(t * NG + g) * 16384;
        #pragma unroll
        for (int j = 0; j < 8; ++j) {
            f32x4 acc = {0.f, 0.f, 0.f, 0.f};
            acc = MFMA16(uf[j][0], xf[0], acc, 0, 0, 0);
            acc = MFMA16(uf[j][1], xf[1], acc, 0, 0, 0);
            const int rt = 128 * w + 16 * j;
            uint2 pk;
            pk.x = pack2(acc[0] + bh4[j].x, acc[1] + bh4[j].y);
            pk.y = pack2(acc[2] + bh4[j].z, acc[3] + bh4[j].w);
            *(uint2*)(ut + ln * 1024 + 2 * (rt + 4 * lg)) = pk;   // [b][r]
        }
    }
}

// ---- RNN kernel: 1 block per group, 8 waves, NO inter-block communication ----
// mfma(W, h): A = W rows (regs+LDS), B = h from LDS [b][r] (XOR-swizzled).
// D: lane holds 4 consecutive h rows for batch ln -> vectorized uint2 publishes.
__global__ void __launch_bounds__(512, 2) rnn_kernel(
    const float* __restrict__ h0, const float* __restrict__ W_h,
    f16* __restrict__ uh, float* __restrict__ out)
{
    extern __shared__ char smem[];
    const int tid = threadIdx.x;
    const int w = tid >> 6, l = tid & 63, lg = l >> 4, ln = l & 15;
    const int g = blockIdx.x;
    const int b0 = g * GB;
    const int rw = w * 64;                     // wave's first output row

    // ---- stage W rows [rw, rw+64) as A-frags: fi = ks*4+j; 15 LDS + 49 reg ----
    half8 wfr[NRW];
    #pragma unroll
    for (int j = 0; j < 4; ++j) {
        const float* wr = W_h + (size_t)(rw + 16 * j + ln) * R_;
        #pragma unroll
        for (int ks = 0; ks < 16; ++ks) {
            const float* p = wr + 32 * ks + 8 * lg;
            half8 f = cvt_h8(*(const float4*)p, *(const float4*)(p + 4));
            const int fi = ks * 4 + j;
            if (fi < NLW) *(half8*)(smem + ((w * NLW + fi) << 10) + (l << 4)) = f;
            else wfr[fi - NLW] = f;
        }
    }
    // ---- stage h0 into buffer 0 (f16, XOR-swizzled [b][r]); 512 threads ----
    {
        const int b = tid >> 5, r0 = (tid & 31) * 16;
        const int sb = (b & 7) << 4;
        const float* hp = h0 + (size_t)(b0 + b) * R_ + r0;
        #pragma unroll
        for (int q = 0; q < 4; ++q) {
            float4 v = *(const float4*)(hp + 4 * q);
            uint2 pk;
            pk.x = pack2(v.x, v.y); pk.y = pack2(v.z, v.w);
            *(uint2*)(smem + HOFF + b * 1024 + ((2 * (r0 + 4 * q)) ^ sb)) = pk;
        }
    }
    // ---- prefetch u[0] for this wave's rows (uint2 from [b][r] slab) ----
    uint2 uu[4];
    #pragma unroll
    for (int j = 0; j < 4; ++j)
        uu[j] = *(const uint2*)((char*)uh + (size_t)g * 16384 + ln * 1024 + 2 * (rw + 16 * j + 4 * lg));
    __syncthreads();   // one-time full barrier after staging

    const int asb = (ln & 7) << 4;   // swizzle mask (b = ln)

    #pragma unroll 1
    for (int t = 0; t < T_; ++t) {
        char* hc = smem + HOFF + (t & 1) * HBYTES;
        char* hn = smem + HOFF + ((t & 1) ^ 1) * HBYTES;
        char* slot = (char*)uh + (size_t)(t * NG + g) * 16384;   // u[t] in, h[t+1] out ([b][r])
        const bool lastt = (t == T_ - 1);

        // acc <- u[t]  (rows rw+16j+4lg..+3, batch ln — matches D layout)
        f32x4 acc[4];
        #pragma unroll
        for (int j = 0; j < 4; ++j) {
            union { uint2 u; f16 h[4]; } c; c.u = uu[j];
            acc[j] = (f32x4){(float)c.h[0], (float)c.h[1], (float)c.h[2], (float)c.h[3]};
        }
        // prefetch u[t+1] early (latency hides under MFMA loop; compiler's counted
        // vmcnt before next step's acc-init keeps h-stores un-drained)
        if (!lastt) {
            const char* un = (const char*)uh + (size_t)((t + 1) * NG + g) * 16384;
            #pragma unroll
            for (int j = 0; j < 4; ++j)
                uu[j] = *(const uint2*)(un + ln * 1024 + 2 * (rw + 16 * j + 4 * lg));
        }
        // ---- W.h over k=512: 16 ks; B-frag h from LDS; A-frag W from LDS/regs ----
        #pragma unroll
        for (int ks = 0; ks < 16; ++ks) {
            half8 hb = *(const half8*)(hc + ln * 1024 + ((64 * ks + 16 * lg) ^ asb));
            #pragma unroll
            for (int j = 0; j < 4; ++j) {
                const int fi = ks * 4 + j;
                half8 aa;
                if (fi < NLW) aa = *(const half8*)(smem + ((w * NLW + fi) << 10) + (l << 4));
                else aa = wfr[fi - NLW];
                acc[j] = MFMA16(aa, hb, acc[j], 0, 0, 0);
            }
        }
        // ---- finalize: tanh, publish h (global slot + LDS next buffer), uint2 ----
        #pragma unroll
        for (int j = 0; j < 4; ++j) {
            const int rb = 2 * (rw + 16 * j + 4 * lg);   // byte offset of 4-row group
            float v0 = tanh_fast(acc[j][0]), v1 = tanh_fast(acc[j][1]);
            float v2 = tanh_fast(acc[j][2]), v3 = tanh_fast(acc[j][3]);
            uint2 pk;
            pk.x = pack2(v0, v1); pk.y = pack2(v2, v3);
            *(uint2*)(slot + ln * 1024 + rb) = pk;               // h history, plain [b][r]
            if (!lastt) {
                *(uint2*)(hn + ln * 1024 + (rb ^ asb)) = pk;     // LDS next buffer (swizzled)
            } else {
                float* xd = out + (size_t)B_ * T_ * O_ + (size_t)(b0 + ln) * R_ + (rw + 16 * j + 4 * lg);
                float4 xv = make_float4(v0, v1, v2, v3);
                *(float4*)xd = xv;
                *(float4*)(xd + (size_t)B_ * R_) = xv;
            }
        }
        // Raw barrier: publish LDS h only (lgkmcnt). Global h-history stores and
        // u-prefetch stay in flight -- no vmcnt(0) drain on the per-step path.
        // Cross-wave data is LDS-only; slot rows are wave-private.
        asm volatile("s_waitcnt lgkmcnt(0)\n\ts_barrier" ::: "memory");
    }
}

// ---------------- post-kernel: y[b][t][o] = W_out . h + b_out ----------------
// h history is [b][r] -> vectorized b128 loads.
__global__ void __launch_bounds__(256) y_kernel(
    const f16* __restrict__ hbuf, const float* __restrict__ W_out,
    const float* __restrict__ b_out, float* __restrict__ out)
{
    const int tid = threadIdx.x;
    const int w = tid >> 6, l = tid & 63, lg = l >> 4, ln = l & 15;
    const int g = blockIdx.x & 7, tc = blockIdx.x >> 3;
    const int b0 = g * GB;

    half8 wf[16];
    #pragma unroll
    for (int ks = 0; ks < 16; ++ks) {
        const float* p = W_out + (size_t)(16 * w + ln) * R_ + 32 * ks + 8 * lg;
        wf[ks] = cvt_h8(*(const float4*)p, *(const float4*)(p + 4));
    }
    const float bo = b_out[16 * w + ln];

    for (int tt = 0; tt < 4; ++tt) {
        const int t = tc * 4 + tt;
        const char* hb = (const char*)hbuf + (size_t)(t * NG + g) * 16384;   // [b][r]
        f32x4 acc = {0.f, 0.f, 0.f, 0.f};
        #pragma unroll
        for (int ks = 0; ks < 16; ++ks) {
            half8 a = *(const half8*)(hb + ln * 1024 + 64 * ks + 16 * lg);
            acc = MFMA16(a, wf[ks], acc, 0, 0, 0);
        }
        #pragma unroll
        for (int q = 0; q < 4; ++q) {
            const int b = 4 * lg + q;
            out[((size_t)(b0 + b) * T_ + t) * O_ + 16 * w + ln] = acc[q] + bo;
        }
    }
}

extern "C" void kernel_launch(void* const* d_in, const int* in_sizes, int n_in,
                              void* d_out, int out_size, void* d_ws, size_t ws_size,
                              hipStream_t stream) {
    const float* x_pred = (const float*)d_in[0];
    const float* h0     = (const float*)d_in[1];
    const float* W_h    = (const float*)d_in[2];
    const float* b_h    = (const float*)d_in[3];
    const float* U_h    = (const float*)d_in[4];
    const float* W_out  = (const float*)d_in[5];
    const float* b_out  = (const float*)d_in[6];
    float* out = (float*)d_out;

    // workspace: u[t][g][b][r] f16 (overwritten in-place by h[t+1]) = 64 MB
    f16* ubuf = (f16*)d_ws;

    hipFuncSetAttribute(reinterpret_cast<const void*>(rnn_kernel),
                        hipFuncAttributeMaxDynamicSharedMemorySize, SMEM_TOTAL);

    pre_kernel<<<dim3(NG * 128), dim3(256), 0, stream>>>(x_pred, b_h, U_h, ubuf);
    rnn_kernel<<<dim3(NG), dim3(512), SMEM_TOTAL, stream>>>(h0, W_h, ubuf, out);
    y_kernel<<<dim3(NG * 128), dim3(256), 0, stream>>>(ubuf, W_out, b_out, out);
}